// Round 20
// baseline (312.270 us; speedup 1.0000x reference)
//
#include <hip/hip_runtime.h>

#define N_NODES 6000
#define DEG_    16
#define N_EDGES (N_NODES*DEG_)
#define D_MODEL 256
#define D_MSG   64
#define D_FF    1024

typedef __bf16 bf16x8 __attribute__((ext_vector_type(8)));
typedef float floatx4 __attribute__((ext_vector_type(4)));

// drain this wave's LDS queue; with the memory clobber this is a safe
// intra-wave producer->consumer fence (no inter-wave convoy like s_barrier).
#define WSYNC() asm volatile("s_waitcnt lgkmcnt(0)" ::: "memory")

__device__ __forceinline__ float silu_f(float v) {
    return v * __builtin_amdgcn_rcpf(1.0f + __expf(-v));
}
__device__ __forceinline__ float b2f(unsigned short u) {
    union { unsigned int i; float f; } v; v.i = ((unsigned int)u) << 16; return v.f;
}
__device__ __forceinline__ unsigned short f2b(float f) {
    union { float f; unsigned int i; } v; v.f = f;
    unsigned int r = (v.i + 0x7FFFu + ((v.i >> 16) & 1u)) >> 16;
    return (unsigned short)r;
}

// ---------------- fused prep: serial-latency blocks FIRST (tail-hiding) ----------------
#define WSRC_OFF 0
#define WDST_OFF 49152
#define WEDGE_OFF 98304
#define W1_OFF 147456
#define W2_OFF 344064
#define WTOTAL 1130496
#define WCOMB_BLOCKS 256                       // 2 layers x 128 rows (serial 256-iter loops)
#define WFC2_BLOCKS 4
#define BIAS_BLOCKS 1
#define CVT4_BLOCKS (WTOTAL/4/256)             // 1104
#define EMB4_BLOCKS (N_NODES*D_MODEL/4/256)    // 1500
#define GEOM_BLOCKS (N_EDGES/256)              // 375
#define PRE0 WCOMB_BLOCKS
#define PRE1 (PRE0 + WFC2_BLOCKS)
#define PRE2 (PRE1 + BIAS_BLOCKS)
#define PRE3 (PRE2 + CVT4_BLOCKS)
#define PRE4 (PRE3 + EMB4_BLOCKS)
__global__ __launch_bounds__(256) void prep_kernel(
    const float* __restrict__ Wsrc, const float* __restrict__ bsrc,
    const float* __restrict__ Wdst, const float* __restrict__ bdst,
    const float* __restrict__ Wedge, const float* __restrict__ W1,
    const float* __restrict__ W2, const float* __restrict__ b2,
    const float* __restrict__ Wfc, const float* __restrict__ bfc,
    unsigned short* __restrict__ wbf_out,
    const int* __restrict__ an, const float* __restrict__ emb,
    unsigned short* __restrict__ x,
    const float* __restrict__ r, float* __restrict__ d, float* __restrict__ rhat,
    unsigned short* __restrict__ wcomb, float* __restrict__ bcomb,
    float* __restrict__ wfc2, float* __restrict__ out) {
    int b = blockIdx.x;
    int t = threadIdx.x;
    if (b < PRE0) {
        int lp  = 1 + (b >> 7);
        int row = b & 127;
        const float* wmrow = (row < 64) ? (Wsrc + (size_t)lp*16384 + row*256)
                                        : (Wdst + (size_t)lp*16384 + (row-64)*256);
        const float* W2f = W2 + (size_t)(lp-1)*262144;
        float a0 = 0.f, a1 = 0.f, a2 = 0.f, a3 = 0.f;
        int f = t*4;
        #pragma unroll 4
        for (int c = 0; c < 256; ++c) {
            float wm = wmrow[c];
            float4 w2v = *(const float4*)(W2f + (size_t)c*1024 + f);
            a0 = fmaf(wm, w2v.x, a0);
            a1 = fmaf(wm, w2v.y, a1);
            a2 = fmaf(wm, w2v.z, a2);
            a3 = fmaf(wm, w2v.w, a3);
        }
        *(ushort4*)(wcomb + (size_t)(lp-1)*131072 + (size_t)row*1024 + f) =
            make_ushort4(f2b(a0), f2b(a1), f2b(a2), f2b(a3));
    } else if (b < PRE1) {
        int c = (b - PRE0)*256 + t;
        const float* W2f = W2 + 2*262144;
        float acc = 0.f;
        #pragma unroll 4
        for (int k = 0; k < 256; ++k) acc += Wfc[k] * W2f[(size_t)k*1024 + c];
        wfc2[c] = acc;
    } else if (b < PRE2) {
        int lp = 1 + (t >> 7);
        int row = t & 127;
        const float* b2l = b2 + (lp-1)*256;
        const float* wmrow = (row < 64) ? (Wsrc + (size_t)lp*16384 + row*256)
                                        : (Wdst + (size_t)lp*16384 + (row-64)*256);
        float acc = 0.f;
        for (int c = 0; c < 256; ++c) acc += wmrow[c] * b2l[c];
        acc += (row < 64) ? bsrc[lp*64 + row] : bdst[lp*64 + (row-64)];
        bcomb[(lp-1)*128 + row] = acc;
        if (t == 0) {
            float bo = 0.f;
            const float* b23 = b2 + 2*256;
            for (int c = 0; c < 256; ++c) bo += Wfc[c] * b23[c];
            out[0] = bo + bfc[0];
        }
    } else if (b < PRE3) {
        int i = ((b - PRE2)*256 + t) * 4;
        const float* sp;
        if      (i < WDST_OFF)  sp = Wsrc + i;
        else if (i < WEDGE_OFF) sp = Wdst + (i - WDST_OFF);
        else if (i < W1_OFF)    sp = Wedge + (i - WEDGE_OFF);
        else if (i < W2_OFF)    sp = W1 + (i - W1_OFF);
        else                    sp = W2 + (i - W2_OFF);
        float4 v = *(const float4*)sp;
        *(ushort4*)(wbf_out + i) = make_ushort4(f2b(v.x), f2b(v.y), f2b(v.z), f2b(v.w));
    } else if (b < PRE4) {
        int i4 = (b - PRE3)*256 + t;
        int node = i4 >> 6, c4 = i4 & 63;
        float4 v = *(const float4*)(emb + (size_t)an[node]*D_MODEL + c4*4);
        *(ushort4*)(x + (size_t)node*D_MODEL + c4*4) =
            make_ushort4(f2b(v.x), f2b(v.y), f2b(v.z), f2b(v.w));
    } else {
        int e = (b - PRE4)*256 + t;
        float xx = r[e*3+0], yy = r[e*3+1], zz = r[e*3+2];
        float n = sqrtf(xx*xx + yy*yy + zz*zz);
        d[e] = n;
        float inv = 1.0f / n;
        *(float4*)(rhat + (size_t)e*4) = make_float4(xx*inv, yy*inv, zz*inv, 0.f);
    }
}

// ---------------- MFMA bf16 GEMM (TM=64, TN templated) ----------------
#define APITCH 40
#define MCP 72
template<int ACT, int DUALB, int TN>
__global__ __launch_bounds__(256) void mgemm(
    const unsigned short* __restrict__ A, int lda,
    const unsigned short* __restrict__ B1, const unsigned short* __restrict__ B2, int ldb,
    const float* __restrict__ bias1, const float* __restrict__ bias2,
    unsigned short* __restrict__ C, int ldc, int M, int K) {
    constexpr int NF = TN/16;
    __shared__ __align__(16) unsigned short sm[5120];
    unsigned short* As = sm;
    unsigned short* Bs = sm + 2560;
    unsigned short* Cs = sm;
    const int t = threadIdx.x;
    const int w = t >> 6;
    const int lane = t & 63;
    const int lr = lane & 15;
    const int lq = lane >> 4;
    const int n0 = blockIdx.x * TN;
    const int m0 = blockIdx.y * 64;
    const unsigned short* B = B1;
    const float* bias = bias1;
    if (DUALB && blockIdx.x == 1) { B = B2; bias = bias2; }
    const unsigned short* Brow = DUALB ? B : (B + (size_t)n0*ldb);

    const int arow = t >> 2, achk = t & 3;
    const bool bstage = (TN == 64) || (t < TN*4);

    floatx4 acc[NF] = {};
    uint4 pa, pb = make_uint4(0,0,0,0);

    {
        int gm = m0 + arow;
        pa = (gm < M) ? *(const uint4*)(A + (size_t)gm*lda + achk*8) : make_uint4(0,0,0,0);
    }
    if (bstage) pb = *(const uint4*)(Brow + (size_t)arow*ldb + achk*8);

    for (int k0 = 0; k0 < K; k0 += 32) {
        *(uint4*)(&As[arow*APITCH + achk*8]) = pa;
        if (bstage) *(uint4*)(&Bs[arow*APITCH + achk*8]) = pb;
        __syncthreads();
        if (k0 + 32 < K) {
            int kn = k0 + 32;
            int gm = m0 + arow;
            pa = (gm < M) ? *(const uint4*)(A + (size_t)gm*lda + kn + achk*8) : make_uint4(0,0,0,0);
            if (bstage) pb = *(const uint4*)(Brow + (size_t)arow*ldb + kn + achk*8);
        }
        bf16x8 af, bfr[NF];
        af = *(const bf16x8*)(&As[(w*16 + lr)*APITCH + lq*8]);
        #pragma unroll
        for (int ns = 0; ns < NF; ++ns)
            bfr[ns] = *(const bf16x8*)(&Bs[(ns*16 + lr)*APITCH + lq*8]);
        #pragma unroll
        for (int ns = 0; ns < NF; ++ns)
            acc[ns] = __builtin_amdgcn_mfma_f32_16x16x32_bf16(af, bfr[ns], acc[ns], 0,0,0);
        __syncthreads();
    }
    #pragma unroll
    for (int ns = 0; ns < NF; ++ns) {
        int bc = ns*16 + lr;
        float bv = bias[DUALB ? bc : (n0 + bc)];
        #pragma unroll
        for (int rg = 0; rg < 4; ++rg) {
            int lrow = w*16 + lq*4 + rg;
            float v = acc[ns][rg] + bv;
            if (ACT) v = silu_f(v);
            Cs[lrow*MCP + bc] = f2b(v);
        }
    }
    __syncthreads();
    constexpr int RQ = TN/8;
    constexpr int ITERS = 64*RQ/256;
    #pragma unroll
    for (int it = 0; it < ITERS; ++it) {
        int i = t + it*256;
        int row = i/RQ, c8 = i - row*RQ;
        int gm = m0 + row;
        if (gm < M)
            *(uint4*)(C + (size_t)gm*ldc + n0 + c8*8) = *(const uint4*)(Cs + row*MCP + c8*8);
    }
}

// ---------------- angle attention, ONE NODE PER WAVE (no s_barrier) ----------------
// 4 nodes/block, per-wave private LDS region; all phases intra-wave with
// lgkmcnt fences instead of __syncthreads (no inter-wave convoy).
struct AW {
    float xij[16][68];
    float rh[16][4];
    float dv[16];
    float logit[16][17];
    float e[16][17];
    float m[16];
    float zi[16];
    float wgt[16];
};
__global__ __launch_bounds__(256) void angle_kernel(
    const unsigned short* __restrict__ xjxi,   // [N,128] bf16: 0..63 xj, 64..127 xi
    const unsigned short* __restrict__ Wl,     // [64,256] bf16
    const float* __restrict__ bedge,           // [64]
    const float* __restrict__ dd,              // [E]
    const float* __restrict__ rhat,            // [E,4]
    const int*   __restrict__ src,             // [E]
    const float* __restrict__ attn,            // [64] wave-uniform
    unsigned short* __restrict__ xn) {         // [N,64] bf16
    __shared__ AW s[4];
    const int t = threadIdx.x;
    const int w = t >> 6, lane = t & 63;
    const int node = blockIdx.x*4 + w;
    AW& S = s[w];
    const int lr = lane & 15, lq = lane >> 4;

    if (lane < 16) {
        float4 rv = *(const float4*)(rhat + (size_t)(node*DEG_ + lane)*4);
        S.rh[lane][0] = rv.x; S.rh[lane][1] = rv.y; S.rh[lane][2] = rv.z; S.rh[lane][3] = 0.f;
        S.dv[lane] = dd[node*DEG_ + lane];
        S.e[lane][lane] = 0.f;
    }
    {   // xij load: lane -> row lr, cols lq*16..+15 (xj[src] + xi)
        int e = node*DEG_ + lr;
        int se = src[e];
        const unsigned short* pj = xjxi + (size_t)se*128 + lq*16;
        const unsigned short* pi = xjxi + (size_t)node*128 + 64 + lq*16;
        uint4 aj0 = *(const uint4*)pj;
        uint4 aj1 = *(const uint4*)(pj + 8);
        uint4 ai0 = *(const uint4*)pi;
        uint4 ai1 = *(const uint4*)(pi + 8);
        const unsigned short* j0 = (const unsigned short*)&aj0;
        const unsigned short* j1 = (const unsigned short*)&aj1;
        const unsigned short* i0 = (const unsigned short*)&ai0;
        const unsigned short* i1 = (const unsigned short*)&ai1;
        #pragma unroll
        for (int j = 0; j < 8; ++j) {
            S.xij[lr][lq*16 + j]     = b2f(j0[j]) + b2f(i0[j]);
            S.xij[lr][lq*16 + 8 + j] = b2f(j1[j]) + b2f(i1[j]);
        }
    }
    WSYNC();
    // ---- edge projection: RBF(d)[16x256] @ Wl^T, full K per wave (32 MFMA) ----
    {
        const float gamma = 31.875f;
        const float step  = 8.0f / 255.0f;
        float dvv = S.dv[lr];
        floatx4 acc[4] = {};
        #pragma unroll
        for (int ks = 0; ks < 8; ++ks) {
            int kb = ks*32 + lq*8;
            unsigned short a[8];
            #pragma unroll
            for (int j = 0; j < 8; ++j) {
                float ttv = dvv - (float)(kb+j)*step;
                a[j] = f2b(__expf(-gamma*ttv*ttv));
            }
            bf16x8 af = *(const bf16x8*)a;
            #pragma unroll
            for (int nt = 0; nt < 4; ++nt) {
                bf16x8 bf = *(const bf16x8*)(Wl + (size_t)(nt*16 + lr)*256 + kb);
                acc[nt] = __builtin_amdgcn_mfma_f32_16x16x32_bf16(af, bf, acc[nt], 0,0,0);
            }
        }
        #pragma unroll
        for (int nt = 0; nt < 4; ++nt) {
            int col = nt*16 + lr;
            float bv = bedge[col];
            #pragma unroll
            for (int rg = 0; rg < 4; ++rg)
                S.xij[lq*4 + rg][col] += acc[nt][rg] + bv;
        }
    }
    WSYNC();
    // ---- pair loop: 2 pairs per lane (120 unique pairs, symmetric logits) ----
    int pp0 = 0, qq0 = 0, pp1 = 0, qq1 = 0;
    float lg0 = 0.f, lg1 = 0.f;
    #pragma unroll
    for (int rep = 0; rep < 2; ++rep) {
        int id = lane + rep*64;
        if (id < 120) {
            int p = (int)((1.0f + sqrtf(8.0f*(float)id + 1.0f)) * 0.5f);
            int q = id - ((p*(p-1)) >> 1);
            float c = S.rh[p][0]*S.rh[q][0] + S.rh[p][1]*S.rh[q][1] + S.rh[p][2]*S.rh[q][2];
            c = fminf(fmaxf(c, -0.999999f), 0.999999f);
            float c2 = 2.0f * c;
            float tk0 = 1.0f, tk1 = c, acc = 0.f;
            const float* xp = &S.xij[p][0];
            const float* xq = &S.xij[q][0];
            #pragma unroll
            for (int k0 = 0; k0 < 64; k0 += 4) {
                float4 xp4 = *(const float4*)(xp + k0);
                float4 xq4 = *(const float4*)(xq + k0);
                float a0 = attn[k0+0], a1 = attn[k0+1], a2 = attn[k0+2], a3 = attn[k0+3];
                float v0 = tk0 + xp4.x + xq4.x;
                acc = fmaf(a0, silu_f(v0), acc);
                { float tn2 = c2*tk1 - tk0; tk0 = tk1; tk1 = tn2; }
                float v1 = tk0 + xp4.y + xq4.y;
                acc = fmaf(a1, silu_f(v1), acc);
                { float tn2 = c2*tk1 - tk0; tk0 = tk1; tk1 = tn2; }
                float v2 = tk0 + xp4.z + xq4.z;
                acc = fmaf(a2, silu_f(v2), acc);
                { float tn2 = c2*tk1 - tk0; tk0 = tk1; tk1 = tn2; }
                float v3 = tk0 + xp4.w + xq4.w;
                acc = fmaf(a3, silu_f(v3), acc);
                { float tn2 = c2*tk1 - tk0; tk0 = tk1; tk1 = tn2; }
            }
            S.logit[p][q] = acc;
            S.logit[q][p] = acc;
            if (rep == 0) { pp0 = p; qq0 = q; lg0 = acc; }
            else          { pp1 = p; qq1 = q; lg1 = acc; }
        }
    }
    WSYNC();
    if (lane < 16) {                          // per-column max
        int q = lane;
        float mx = -1e30f;
        #pragma unroll
        for (int p = 0; p < 16; ++p) if (p != q) mx = fmaxf(mx, S.logit[p][q]);
        S.m[q] = mx;
    }
    WSYNC();
    if (lane < 120) {                         // rep-0 exps
        S.e[pp0][qq0] = __expf(lg0 - S.m[qq0]);
        S.e[qq0][pp0] = __expf(lg0 - S.m[pp0]);
    }
    if (lane < 56) {                          // rep-1 exps
        S.e[pp1][qq1] = __expf(lg1 - S.m[qq1]);
        S.e[qq1][pp1] = __expf(lg1 - S.m[pp1]);
    }
    WSYNC();
    if (lane < 16) {
        int q = lane;
        float z = 0.f;
        #pragma unroll
        for (int p = 0; p < 16; ++p) z += S.e[p][q];
        S.zi[q] = __builtin_amdgcn_rcpf(z);
    }
    WSYNC();
    if (lane < 16) {
        int p = lane;
        float sw = 0.f;
        #pragma unroll
        for (int q = 0; q < 16; ++q) sw += S.e[p][q] * S.zi[q];
        S.wgt[p] = sw;
    }
    WSYNC();
    {
        float acc = 0.f;
        #pragma unroll
        for (int p = 0; p < 16; ++p) acc += S.wgt[p] * S.xij[p][lane];
        xn[(size_t)node*64 + lane] = f2b(acc);
    }
}

// ---------------- final: out += mean_i (h3[i] . wfc2) ----------------
__global__ __launch_bounds__(256) void reduce2_kernel(const unsigned short* __restrict__ hh,
    const float* __restrict__ wfc2, float* __restrict__ out) {
    __shared__ float s[256];
    int t = threadIdx.x;
    float w0 = wfc2[t*4+0], w1 = wfc2[t*4+1], w2 = wfc2[t*4+2], w3 = wfc2[t*4+3];
    float local = 0.f;
    for (int i = blockIdx.x; i < N_NODES; i += gridDim.x) {
        ushort4 hv = *(const ushort4*)(hh + (size_t)i*D_FF + t*4);
        local += b2f(hv.x)*w0 + b2f(hv.y)*w1 + b2f(hv.z)*w2 + b2f(hv.w)*w3;
    }
    s[t] = local; __syncthreads();
    for (int off = 128; off > 0; off >>= 1) {
        if (t < off) s[t] += s[t+off];
        __syncthreads();
    }
    if (t == 0) atomicAdd(out, s[0] * (1.0f/(float)N_NODES));
}

extern "C" void kernel_launch(void* const* d_in, const int* in_sizes, int n_in,
                              void* d_out, int out_size, void* d_ws, size_t ws_size,
                              hipStream_t stream) {
    (void)in_sizes; (void)n_in; (void)out_size; (void)ws_size;
    const float* r    = (const float*)d_in[0];
    const int*   an   = (const int*)  d_in[1];
    const int*   src  = (const int*)  d_in[2];
    const float* emb  = (const float*)d_in[6];
    const float* Wsrc = (const float*)d_in[7];
    const float* bsrc = (const float*)d_in[8];
    const float* Wdst = (const float*)d_in[9];
    const float* bdst = (const float*)d_in[10];
    const float* Wedge= (const float*)d_in[11];
    const float* bedge= (const float*)d_in[12];
    const float* attn = (const float*)d_in[13];
    const float* W1   = (const float*)d_in[14];
    const float* b1   = (const float*)d_in[15];
    const float* W2   = (const float*)d_in[16];
    const float* b2   = (const float*)d_in[17];
    const float* Wfc  = (const float*)d_in[18];
    const float* bfc  = (const float*)d_in[19];

    char* ws = (char*)d_ws;
    float* d_d              = (float*)(ws);                    // 384000 B
    float* d_rhat           = (float*)(ws + 384000);           // 1536000 B
    unsigned short* wbf     = (unsigned short*)(ws + 1920000); // 2260992 B
    unsigned short* d_x     = (unsigned short*)(ws + 4180992); // 3072000 B
    unsigned short* d_xjxi  = (unsigned short*)(ws + 7252992); // 1536000 B
    unsigned short* d_xn    = (unsigned short*)(ws + 8788992); // 768000 B
    unsigned short* d_h     = (unsigned short*)(ws + 9556992); // 12288000 B
    unsigned short* d_wcomb = (unsigned short*)(ws + 21844992);// 524288 B
    float* d_bcomb          = (float*)(ws + 22369280);         // 1024 B
    float* d_wfc2           = (float*)(ws + 22370304);         // 4096 B
    float* out = (float*)d_out;

    unsigned short* wsrc_bf  = wbf + WSRC_OFF;
    unsigned short* wdst_bf  = wbf + WDST_OFF;
    unsigned short* wedge_bf = wbf + WEDGE_OFF;
    unsigned short* w1_bf    = wbf + W1_OFF;

    prep_kernel<<<PRE4 + GEOM_BLOCKS, 256, 0, stream>>>(
        Wsrc, bsrc, Wdst, bdst, Wedge, W1, W2, b2, Wfc, bfc,
        wbf, an, emb, d_x, r, d_d, d_rhat, d_wcomb, d_bcomb, d_wfc2, out);

    // ---- layer 0 ----
    mgemm<0,1,64><<<dim3(2,94), 256, 0, stream>>>(
        d_x, 256, wsrc_bf, wdst_bf, 256,
        bsrc, bdst, d_xjxi, 128, N_NODES, 256);
    angle_kernel<<<N_NODES/4, 256, 0, stream>>>(
        d_xjxi, wedge_bf, bedge, d_d, d_rhat, src, attn, d_xn);
    mgemm<1,0,64><<<dim3(16,94), 256, 0, stream>>>(
        d_xn, 64, w1_bf, (const unsigned short*)nullptr, 64,
        b1, (const float*)nullptr, d_h, D_FF, N_NODES, 64);
    mgemm<0,0,32><<<dim3(4,94), 256, 0, stream>>>(
        d_h, 1024, d_wcomb, (const unsigned short*)nullptr, 1024,
        d_bcomb, (const float*)nullptr, d_xjxi, 128, N_NODES, 1024);

    // ---- layer 1 ----
    angle_kernel<<<N_NODES/4, 256, 0, stream>>>(
        d_xjxi, wedge_bf + 16384, bedge + 64, d_d, d_rhat, src, attn + 64, d_xn);
    mgemm<1,0,64><<<dim3(16,94), 256, 0, stream>>>(
        d_xn, 64, w1_bf + 65536, (const unsigned short*)nullptr, 64,
        b1 + 1024, (const float*)nullptr, d_h, D_FF, N_NODES, 64);
    mgemm<0,0,32><<<dim3(4,94), 256, 0, stream>>>(
        d_h, 1024, d_wcomb + 131072, (const unsigned short*)nullptr, 1024,
        d_bcomb + 128, (const float*)nullptr, d_xjxi, 128, N_NODES, 1024);

    // ---- layer 2 ----
    angle_kernel<<<N_NODES/4, 256, 0, stream>>>(
        d_xjxi, wedge_bf + 32768, bedge + 128, d_d, d_rhat, src, attn + 128, d_xn);
    mgemm<1,0,64><<<dim3(16,94), 256, 0, stream>>>(
        d_xn, 64, w1_bf + 131072, (const unsigned short*)nullptr, 64,
        b1 + 2048, (const float*)nullptr, d_h, D_FF, N_NODES, 64);
    reduce2_kernel<<<400, 256, 0, stream>>>(d_h, d_wfc2, out);
}